// Round 5
// baseline (676.116 us; speedup 1.0000x reference)
//
#include <hip/hip_runtime.h>

constexpr int N_NODES = 50000;
constexpr int N_EDGES = 1600000;
constexpr int NREL    = 12;
constexpr int F_INPUT = 64;
constexpr int HID     = 128;
constexpr int NCLS    = 10;
constexpr int NGRAPH  = 256;
constexpr int NSEG    = N_NODES * NREL;       // 600000
constexpr int CHUNK   = 1024;
constexpr int NCHUNK  = (NSEG + CHUNK - 1) / CHUNK;  // 586
constexpr float BN_EPS = 1e-5f;

typedef float v4f __attribute__((ext_vector_type(4)));
typedef short s8b __attribute__((ext_vector_type(8)));

__device__ __forceinline__ unsigned f2bf(float f) {
    unsigned u = __float_as_uint(f);
    return (u + 0x7FFFu + ((u >> 16) & 1u)) >> 16;   // RNE fp32->bf16
}
__device__ __forceinline__ unsigned pack2(float a, float b) {
    return f2bf(a) | (f2bf(b) << 16);
}
__device__ __forceinline__ void add8(float* a, uint4 u) {
    a[0] += __uint_as_float(u.x << 16);
    a[1] += __uint_as_float(u.x & 0xFFFF0000u);
    a[2] += __uint_as_float(u.y << 16);
    a[3] += __uint_as_float(u.y & 0xFFFF0000u);
    a[4] += __uint_as_float(u.z << 16);
    a[5] += __uint_as_float(u.z & 0xFFFF0000u);
    a[6] += __uint_as_float(u.w << 16);
    a[7] += __uint_as_float(u.w & 0xFFFF0000u);
}

// ---------------- fused prep: zero scratch + pack weights + cast x ----------------
constexpr int PR0 = 150000;               // cnt: 600000 ints = 150000 uint4
constexpr int PR1 = PR0 + 64;             // bn1: 256 floats
constexpr int PR2 = PR1 + 64;             // bn2: 256 floats
constexpr int PR3 = PR2 + 8192;           // psum: 32768 floats
constexpr int PR4 = PR3 + 64;             // pcnt: 256 floats
constexpr int PR5 = PR4 + 13 * F_INPUT * HID;   // pack_w1: 106496
constexpr int PR6 = PR5 + 13 * HID * HID;       // pack_w2: 212992
constexpr int PR7 = PR6 + N_NODES * F_INPUT / 4; // to_bf16: 800000
constexpr int PREP_BLOCKS = (PR7 + 255) / 256;

__global__ void prep(const float* __restrict__ Wrel1, const float* __restrict__ root1,
                     const float* __restrict__ Wrel2, const float* __restrict__ root2,
                     const float* __restrict__ x,
                     ushort* __restrict__ Wp1, ushort* __restrict__ Wp2,
                     ushort* __restrict__ xb,
                     int* __restrict__ cnt, float* __restrict__ bn1, float* __restrict__ bn2,
                     float* __restrict__ psum, float* __restrict__ pcnt) {
    int tid = blockIdx.x * 256 + threadIdx.x;
    const uint4 z = make_uint4(0, 0, 0, 0);
    if (tid < PR0) { reinterpret_cast<uint4*>(cnt)[tid] = z; return; }
    if (tid < PR1) { reinterpret_cast<uint4*>(bn1)[tid - PR0] = z; return; }
    if (tid < PR2) { reinterpret_cast<uint4*>(bn2)[tid - PR1] = z; return; }
    if (tid < PR3) { reinterpret_cast<uint4*>(psum)[tid - PR2] = z; return; }
    if (tid < PR4) { reinterpret_cast<uint4*>(pcnt)[tid - PR3] = z; return; }
    if (tid < PR5) {
        int idx = tid - PR4;                       // 13 * 8192
        int r = idx >> 13, rem = idx & 8191;
        int k = rem >> 7, n = rem & 127;
        const float* W = (r < NREL) ? (Wrel1 + (size_t)r * 8192) : root1;
        float v = W[k * HID + n];
        int b = k >> 5, kk = k & 31;
        Wp1[(((size_t)(r * 2 + b)) * HID + n) * 32 + kk] = (ushort)f2bf(v);
        return;
    }
    if (tid < PR6) {
        int idx = tid - PR5;                       // 13 * 16384
        int r = idx >> 14, rem = idx & 16383;
        int k = rem >> 7, n = rem & 127;
        const float* W = (r < NREL) ? (Wrel2 + (size_t)r * 16384) : root2;
        float v = W[k * HID + n];
        int b = k >> 5, kk = k & 31;
        Wp2[(((size_t)(r * 4 + b)) * HID + n) * 32 + kk] = (ushort)f2bf(v);
        return;
    }
    if (tid < PR7) {
        int i = tid - PR6;
        float4 v = reinterpret_cast<const float4*>(x)[i];
        uint2 o;
        o.x = pack2(v.x, v.y);
        o.y = pack2(v.z, v.w);
        reinterpret_cast<uint2*>(xb)[i] = o;
    }
}

// ---------------- CSR build ----------------

constexpr int CE0 = N_EDGES / 4;          // 400000 edge-quads
constexpr int CE1 = CE0 + N_NODES / 4;    // + 12500 node-quads

__global__ void count_ek(const int* __restrict__ dst, const int* __restrict__ et,
                         int* __restrict__ cnt, const int* __restrict__ batch,
                         float* __restrict__ pcnt) {
    int tid = blockIdx.x * 256 + threadIdx.x;
    if (tid < CE0) {
        int4 d = reinterpret_cast<const int4*>(dst)[tid];
        int4 tt = reinterpret_cast<const int4*>(et)[tid];
        atomicAdd(&cnt[d.x * NREL + tt.x], 1);
        atomicAdd(&cnt[d.y * NREL + tt.y], 1);
        atomicAdd(&cnt[d.z * NREL + tt.z], 1);
        atomicAdd(&cnt[d.w * NREL + tt.w], 1);
    } else if (tid < CE1) {
        int4 b = reinterpret_cast<const int4*>(batch)[tid - CE0];
        atomicAdd(&pcnt[b.x], 1.0f);
        atomicAdd(&pcnt[b.y], 1.0f);
        atomicAdd(&pcnt[b.z], 1.0f);
        atomicAdd(&pcnt[b.w], 1.0f);
    }
}

__global__ void scan_a(const int* __restrict__ cnt, int* __restrict__ csum) {
    __shared__ int red[256];
    int b = blockIdx.x, t = threadIdx.x;
    int base = b * CHUNK + t * 4;
    int s = 0;
#pragma unroll
    for (int j = 0; j < 4; ++j) {
        int i = base + j;
        if (i < NSEG) s += cnt[i];
    }
    red[t] = s;
    __syncthreads();
    for (int d = 128; d > 0; d >>= 1) {
        if (t < d) red[t] += red[t + d];
        __syncthreads();
    }
    if (t == 0) csum[b] = red[0];
}

__global__ void scan_b(const int* __restrict__ csum, int* __restrict__ coff) {
    __shared__ int s[1024];
    int t = threadIdx.x;
    s[t] = (t < NCHUNK) ? csum[t] : 0;
    __syncthreads();
    for (int d = 1; d < 1024; d <<= 1) {
        int v = (t >= d) ? s[t - d] : 0;
        __syncthreads();
        s[t] += v;
        __syncthreads();
    }
    if (t < NCHUNK) coff[t] = (t == 0) ? 0 : s[t - 1];
}

__global__ void scan_c(const int* __restrict__ cnt, const int* __restrict__ coff,
                       int* __restrict__ off, int* __restrict__ cursor) {
    __shared__ int ts[256];
    int b = blockIdx.x, t = threadIdx.x;
    int base = b * CHUNK + t * 4;
    int c[4];
    int s = 0;
#pragma unroll
    for (int j = 0; j < 4; ++j) {
        int i = base + j;
        c[j] = (i < NSEG) ? cnt[i] : 0;
        s += c[j];
    }
    ts[t] = s;
    __syncthreads();
    for (int d = 1; d < 256; d <<= 1) {
        int v = (t >= d) ? ts[t - d] : 0;
        __syncthreads();
        ts[t] += v;
        __syncthreads();
    }
    int run = coff[b] + ((t == 0) ? 0 : ts[t - 1]);
#pragma unroll
    for (int j = 0; j < 4; ++j) {
        int i = base + j;
        if (i < NSEG) {
            off[i] = run;
            cursor[i] = run;
            run += c[j];
        }
    }
    if (b == 0 && t == 0) off[NSEG] = N_EDGES;
}

__global__ void fill_csr(const int* __restrict__ src, const int* __restrict__ dst,
                         const int* __restrict__ et, int* __restrict__ cursor,
                         int* __restrict__ csr_src) {
    int tid = blockIdx.x * 256 + threadIdx.x;
    if (tid < CE0) {
        int4 s = reinterpret_cast<const int4*>(src)[tid];
        int4 d = reinterpret_cast<const int4*>(dst)[tid];
        int4 tt = reinterpret_cast<const int4*>(et)[tid];
        csr_src[atomicAdd(&cursor[d.x * NREL + tt.x], 1)] = s.x;
        csr_src[atomicAdd(&cursor[d.y * NREL + tt.y], 1)] = s.y;
        csr_src[atomicAdd(&cursor[d.z * NREL + tt.z], 1)] = s.z;
        csr_src[atomicAdd(&cursor[d.w * NREL + tt.w], 1)] = s.w;
    }
}

// ---------------- fused RGCN layer (MFMA), 32-node tiles ----------------
// Staging: 8 threads/node, 4-edge unrolled; all 4 row-gathers issue with
// CLAMPED indices (always valid), adds predicated -> max MLP, no divergent
// address chains. MFMA: wave -> (row-tile, col-half), fp32 accum.

template <int F>
__launch_bounds__(256)
__global__ void rgcn_mfma(const ushort* __restrict__ xin, const ushort* __restrict__ Wp,
                          const float* __restrict__ bias,
                          const int* __restrict__ off, const int* __restrict__ csr,
                          float* __restrict__ out, float* __restrict__ bn_sum,
                          float* __restrict__ bn_sq) {
    constexpr int TN  = 32;
    constexpr int FP2 = F + 8;       // padded LDS row (bf16 elems)
    constexpr int F8  = F / 8;       // bf16 elems per staging thread
    constexpr int NLD = F8 / 8;      // uint4 loads per staging thread (1 or 2)
    constexpr int KB  = F / 32;      // K-blocks per relation
    __shared__ __align__(16) ushort A[TN * FP2];
    __shared__ int OFF[TN][14];

    const int t = threadIdx.x;
    const int n0 = blockIdx.x * TN;
    const int nl = t >> 3, tid8 = t & 7;
    const int lane = t & 63, wave = t >> 6;
    const int q = lane >> 4, l16 = lane & 15;
    const int rt = wave & 1, ch = wave >> 1;
    const int nglob = n0 + nl;

    // preload all 13 segment boundaries for this node
    {
        bool ok = nglob < N_NODES;
        int n12 = nglob * NREL;
        OFF[nl][tid8] = ok ? off[n12 + tid8] : 0;
        if (tid8 < 5) OFF[nl][8 + tid8] = ok ? off[n12 + 8 + tid8] : 0;
    }

    v4f acc[4];
#pragma unroll
    for (int nt = 0; nt < 4; ++nt) acc[nt] = (v4f){0.f, 0.f, 0.f, 0.f};

    uint4* Aw = reinterpret_cast<uint4*>(A + nl * FP2 + tid8 * F8);
    const ushort* xbase = xin + tid8 * F8;
    const ushort* Arow = A + (rt * 16 + l16) * FP2;

    __syncthreads();

    for (int rel = 0; rel <= NREL; ++rel) {
        // ---- stage A tile ----
        if (rel < NREL) {
            float accs[F8];
#pragma unroll
            for (int i = 0; i < F8; ++i) accs[i] = 0.f;
            int e0 = OFF[nl][rel], e1 = OFF[nl][rel + 1];
            for (int e = e0; e < e1; e += 4) {
                int elast = e1 - 1;
                int i0 = csr[e];
                int i1 = csr[min(e + 1, elast)];
                int i2 = csr[min(e + 2, elast)];
                int i3 = csr[min(e + 3, elast)];
                const uint4* p0 = reinterpret_cast<const uint4*>(xbase + (size_t)i0 * F);
                const uint4* p1 = reinterpret_cast<const uint4*>(xbase + (size_t)i1 * F);
                const uint4* p2 = reinterpret_cast<const uint4*>(xbase + (size_t)i2 * F);
                const uint4* p3 = reinterpret_cast<const uint4*>(xbase + (size_t)i3 * F);
#pragma unroll
                for (int c = 0; c < NLD; ++c) {
                    uint4 u0 = p0[c];
                    uint4 u1 = p1[c];
                    uint4 u2 = p2[c];
                    uint4 u3 = p3[c];
                    add8(accs + c * 8, u0);
                    if (e + 1 < e1) add8(accs + c * 8, u1);
                    if (e + 2 < e1) add8(accs + c * 8, u2);
                    if (e + 3 < e1) add8(accs + c * 8, u3);
                }
            }
            int cntE = e1 - e0;
            float inv = (cntE > 0) ? 1.0f / (float)cntE : 0.f;
#pragma unroll
            for (int c = 0; c < NLD; ++c) {
                uint4 o;
                o.x = pack2(accs[c * 8 + 0] * inv, accs[c * 8 + 1] * inv);
                o.y = pack2(accs[c * 8 + 2] * inv, accs[c * 8 + 3] * inv);
                o.z = pack2(accs[c * 8 + 4] * inv, accs[c * 8 + 5] * inv);
                o.w = pack2(accs[c * 8 + 6] * inv, accs[c * 8 + 7] * inv);
                Aw[c] = o;
            }
        } else {  // root term: own features (already bf16)
            if (nglob < N_NODES) {
                const uint4* r0 = reinterpret_cast<const uint4*>(xbase + (size_t)nglob * F);
#pragma unroll
                for (int c = 0; c < NLD; ++c) Aw[c] = r0[c];
            } else {
                uint4 z = make_uint4(0, 0, 0, 0);
#pragma unroll
                for (int c = 0; c < NLD; ++c) Aw[c] = z;
            }
        }
        __syncthreads();
        // ---- MFMA accumulate ----
#pragma unroll
        for (int b = 0; b < KB; ++b) {
            s8b af = *reinterpret_cast<const s8b*>(Arow + b * 32 + q * 8);
            const ushort* wb =
                Wp + ((size_t)(rel * KB + b) * HID + ch * 64 + l16) * 32 + q * 8;
#pragma unroll
            for (int nt = 0; nt < 4; ++nt) {
                s8b bfb = *reinterpret_cast<const s8b*>(wb + (size_t)nt * 16 * 32);
                acc[nt] = __builtin_amdgcn_mfma_f32_16x16x32_bf16(af, bfb, acc[nt], 0, 0, 0);
            }
        }
        __syncthreads();
    }

    // ---- epilogue: bias + store + BN partials ----
    float* REDs = reinterpret_cast<float*>(A);       // [4][64]
    float* REDq = REDs + 256;                        // [4][64]
#pragma unroll
    for (int nt = 0; nt < 4; ++nt) {
        int col = ch * 64 + nt * 16 + l16;
        float bcol = bias[col];
        float s = 0.f, s2 = 0.f;
#pragma unroll
        for (int r = 0; r < 4; ++r) {
            int n = n0 + rt * 16 + q * 4 + r;
            if (n < N_NODES) {
                float v = acc[nt][r] + bcol;
                out[(size_t)n * HID + col] = v;
                s += v;
                s2 += v * v;
            }
        }
        s += __shfl_xor(s, 16);  s += __shfl_xor(s, 32);
        s2 += __shfl_xor(s2, 16); s2 += __shfl_xor(s2, 32);
        if (lane < 16) {
            REDs[wave * 64 + nt * 16 + l16] = s;
            REDq[wave * 64 + nt * 16 + l16] = s2;
        }
    }
    __syncthreads();
    if (t < 128) {
        int chc = t >> 6, cl = t & 63;
        float vs = REDs[(2 * chc) * 64 + cl] + REDs[(2 * chc + 1) * 64 + cl];
        float vq = REDq[(2 * chc) * 64 + cl] + REDq[(2 * chc + 1) * 64 + cl];
        atomicAdd(&bn_sum[t], vs);
        atomicAdd(&bn_sq[t], vq);
    }
}

// ---------------- BN(+finalize) + ReLU, emit bf16 ----------------

__global__ void bn_relu_bf16(const float* __restrict__ h, const float* __restrict__ bn_sum,
                             const float* __restrict__ bn_sq, const float* __restrict__ gamma,
                             const float* __restrict__ beta, ushort* __restrict__ outb) {
    __shared__ float CA[HID], CB[HID];
    int t = threadIdx.x;
    if (t < HID) {
        float mu = bn_sum[t] * (1.0f / N_NODES);
        float var = bn_sq[t] * (1.0f / N_NODES) - mu * mu;
        float a = gamma[t] / sqrtf(var + BN_EPS);
        CA[t] = a;
        CB[t] = beta[t] - a * mu;
    }
    __syncthreads();
    int i = blockIdx.x * 256 + t;  // float4 index
    constexpr int TOTAL = N_NODES * HID / 4;
    if (i < TOTAL) {
        int o4 = i & 31;
        float4 a = reinterpret_cast<const float4*>(CA)[o4];
        float4 b = reinterpret_cast<const float4*>(CB)[o4];
        float4 v = reinterpret_cast<const float4*>(h)[i];
        v.x = fmaxf(a.x * v.x + b.x, 0.f);
        v.y = fmaxf(a.y * v.y + b.y, 0.f);
        v.z = fmaxf(a.z * v.z + b.z, 0.f);
        v.w = fmaxf(a.w * v.w + b.w, 0.f);
        uint2 o;
        o.x = pack2(v.x, v.y);
        o.y = pack2(v.z, v.w);
        reinterpret_cast<uint2*>(outb)[i] = o;
    }
}

// ---------------- pooling (BN finalize + ReLU fused; batch sorted -> run-length) ----------------

__global__ void pool_bnrelu(const float* __restrict__ h, const float* __restrict__ bn_sum,
                            const float* __restrict__ bn_sq, const float* __restrict__ gamma,
                            const float* __restrict__ beta, const int* __restrict__ batch,
                            float* __restrict__ psum) {
    __shared__ float CA[HID], CB[HID];
    int t = threadIdx.x;
    if (t < HID) {
        float mu = bn_sum[t] * (1.0f / N_NODES);
        float var = bn_sq[t] * (1.0f / N_NODES) - mu * mu;
        float a = gamma[t] / sqrtf(var + BN_EPS);
        CA[t] = a;
        CB[t] = beta[t] - a * mu;
    }
    __syncthreads();
    int col = t & 127;
    int nb = blockIdx.x * 16 + (t >> 7) * 8;  // 8 consecutive nodes per thread
    float a = CA[col], b = CB[col];
    float run = 0.f;
    int curg = -1;
    for (int i = 0; i < 8; ++i) {
        int n = nb + i;
        if (n < N_NODES) {
            int g = batch[n];
            float v = fmaxf(a * h[(size_t)n * HID + col] + b, 0.f);
            if (g != curg) {
                if (curg >= 0) atomicAdd(&psum[curg * HID + col], run);
                run = 0.f;
                curg = g;
            }
            run += v;
        }
    }
    if (curg >= 0) atomicAdd(&psum[curg * HID + col], run);
}

__global__ void final_kernel(const float* __restrict__ psum, const float* __restrict__ pcnt,
                             const float* __restrict__ Wf, const float* __restrict__ bf,
                             float* __restrict__ out) {
    __shared__ float p[HID];
    int g = blockIdx.x, t = threadIdx.x;  // 64 threads
    float inv = 1.0f / fmaxf(pcnt[g], 1.0f);
    p[t] = psum[g * HID + t] * inv;
    p[t + 64] = psum[g * HID + t + 64] * inv;
    __syncthreads();
    if (t < NCLS) {
        float s = bf[t];
#pragma unroll 16
        for (int k = 0; k < HID; ++k) s += p[k] * Wf[k * NCLS + t];
        out[g * NCLS + t] = s;
    }
}

// ---------------- launch ----------------

extern "C" void kernel_launch(void* const* d_in, const int* in_sizes, int n_in,
                              void* d_out, int out_size, void* d_ws, size_t ws_size,
                              hipStream_t stream) {
    const float* x      = (const float*)d_in[0];
    const float* Wrel1  = (const float*)d_in[1];
    const float* root1  = (const float*)d_in[2];
    const float* bias1  = (const float*)d_in[3];
    const float* gamma1 = (const float*)d_in[4];
    const float* beta1  = (const float*)d_in[5];
    const float* Wrel2  = (const float*)d_in[6];
    const float* root2  = (const float*)d_in[7];
    const float* bias2  = (const float*)d_in[8];
    const float* gamma2 = (const float*)d_in[9];
    const float* beta2  = (const float*)d_in[10];
    const float* Wf     = (const float*)d_in[11];
    const float* bf     = (const float*)d_in[12];
    const int* ei       = (const int*)d_in[13];
    const int* et       = (const int*)d_in[14];
    const int* batch    = (const int*)d_in[15];
    const int* srcv = ei;
    const int* dstv = ei + N_EDGES;

    char* w = (char*)d_ws;
    auto alloc = [&](size_t bytes) -> char* {
        char* p = w;
        w += (bytes + 255) / 256 * 256;
        return p;
    };
    int* cnt     = (int*)alloc((size_t)NSEG * 4);
    int* off     = (int*)alloc((size_t)(NSEG + 1) * 4);
    int* cursor  = (int*)alloc((size_t)NSEG * 4);
    int* csr     = (int*)alloc((size_t)N_EDGES * 4);
    int* csum    = (int*)alloc((size_t)NCHUNK * 4);
    int* coff    = (int*)alloc((size_t)NCHUNK * 4);
    float* H1    = (float*)alloc((size_t)N_NODES * HID * 4);
    float* H2    = (float*)alloc((size_t)N_NODES * HID * 4);
    ushort* xb   = (ushort*)alloc((size_t)N_NODES * F_INPUT * 2);
    ushort* H1b  = (ushort*)alloc((size_t)N_NODES * HID * 2);
    ushort* Wp1  = (ushort*)alloc((size_t)13 * F_INPUT * HID * 2);
    ushort* Wp2  = (ushort*)alloc((size_t)13 * HID * HID * 2);
    float* bn1   = (float*)alloc(2 * HID * 4);  // sum | sq
    float* bn2   = (float*)alloc(2 * HID * 4);
    float* psum  = (float*)alloc((size_t)NGRAPH * HID * 4);
    float* pcnt  = (float*)alloc((size_t)NGRAPH * 4);

    prep<<<PREP_BLOCKS, 256, 0, stream>>>(Wrel1, root1, Wrel2, root2, x,
                                          Wp1, Wp2, xb, cnt, bn1, bn2, psum, pcnt);

    count_ek<<<(CE1 + 255) / 256, 256, 0, stream>>>(dstv, et, cnt, batch, pcnt);
    scan_a<<<NCHUNK, 256, 0, stream>>>(cnt, csum);
    scan_b<<<1, 1024, 0, stream>>>(csum, coff);
    scan_c<<<NCHUNK, 256, 0, stream>>>(cnt, coff, off, cursor);
    fill_csr<<<(CE0 + 255) / 256, 256, 0, stream>>>(srcv, dstv, et, cursor, csr);

    int nblk = (N_NODES + 31) / 32;  // 1563
    rgcn_mfma<F_INPUT><<<nblk, 256, 0, stream>>>(xb, Wp1, bias1, off, csr, H1, bn1, bn1 + HID);
    bn_relu_bf16<<<(N_NODES * HID / 4 + 255) / 256, 256, 0, stream>>>(H1, bn1, bn1 + HID,
                                                                      gamma1, beta1, H1b);

    rgcn_mfma<HID><<<nblk, 256, 0, stream>>>(H1b, Wp2, bias2, off, csr, H2, bn2, bn2 + HID);

    pool_bnrelu<<<(N_NODES + 15) / 16, 256, 0, stream>>>(H2, bn2, bn2 + HID, gamma2, beta2,
                                                         batch, psum);
    final_kernel<<<NGRAPH, 64, 0, stream>>>(psum, pcnt, Wf, bf, (float*)d_out);
}